// Round 2
// baseline (106.669 us; speedup 1.0000x reference)
//
#include <hip/hip_runtime.h>
#include <hip/hip_fp16.h>

#define D 64

typedef _Float16 h16;
typedef h16 h16x2 __attribute__((ext_vector_type(2)));
typedef float f32x4 __attribute__((ext_vector_type(4)));

__device__ __forceinline__ h16x2 u2h(unsigned int u) {
    union { unsigned int i; h16x2 h; } t; t.i = u; return t.h;
}

// dot of 8 f16 pairs (two uint4-packed rows), f32 accumulate
__device__ __forceinline__ float dot8_f16(uint4 a, uint4 b, float c) {
#if __has_builtin(__builtin_amdgcn_fdot2)
    c = __builtin_amdgcn_fdot2(u2h(a.x), u2h(b.x), c, false);
    c = __builtin_amdgcn_fdot2(u2h(a.y), u2h(b.y), c, false);
    c = __builtin_amdgcn_fdot2(u2h(a.z), u2h(b.z), c, false);
    c = __builtin_amdgcn_fdot2(u2h(a.w), u2h(b.w), c, false);
    return c;
#else
    float2 t;
    t = __half22float2(*(const __half2*)&a.x); float2 s = __half22float2(*(const __half2*)&b.x);
    c = fmaf(t.x, s.x, c); c = fmaf(t.y, s.y, c);
    t = __half22float2(*(const __half2*)&a.y); s = __half22float2(*(const __half2*)&b.y);
    c = fmaf(t.x, s.x, c); c = fmaf(t.y, s.y, c);
    t = __half22float2(*(const __half2*)&a.z); s = __half22float2(*(const __half2*)&b.z);
    c = fmaf(t.x, s.x, c); c = fmaf(t.y, s.y, c);
    t = __half22float2(*(const __half2*)&a.w); s = __half22float2(*(const __half2*)&b.w);
    c = fmaf(t.x, s.x, c); c = fmaf(t.y, s.y, c);
    return c;
#endif
}

// acc[q] += (float)x.h[q] * s  — written so LLVM folds the f16 extend into
// v_fma_mix_f32 (one instr per element instead of cvt+fma).
__device__ __forceinline__ void fma8_mix(uint4 x, float s, float acc[8]) {
    union { uint4 u; __half h[8]; } t; t.u = x;
#pragma unroll
    for (int q = 0; q < 8; ++q) acc[q] = fmaf(__half2float(t.h[q]), s, acc[q]);
}

// ---------------------------------------------------------------------------
// Kernel 1 (merged): blocks [0, gemmBlocks) compute Xp = f16(X @ W);
// blocks [gemmBlocks, ...) build CSR rowptr from sorted `row`.
// (unchanged — ~7 us, not the bottleneck)
// ---------------------------------------------------------------------------
__global__ __launch_bounds__(256) void prep_kernel(const float* __restrict__ X,
                                                   const float* __restrict__ W,
                                                   const int* __restrict__ row,
                                                   __half* __restrict__ Xp,
                                                   int* __restrict__ rowptr,
                                                   int nNodes, int nEdges,
                                                   int gemmBlocks) {
    if ((int)blockIdx.x >= gemmBlocks) {
        int e = (blockIdx.x - gemmBlocks) * 256 + threadIdx.x;
        if (e >= nEdges) return;
        int r = row[e];
        int rprev = (e == 0) ? -1 : row[e - 1];
        for (int q = rprev + 1; q <= r; ++q) rowptr[q] = e;
        if (e == nEdges - 1) {
            for (int q = r + 1; q <= nNodes; ++q) rowptr[q] = nEdges;
        }
        return;
    }
    int lane = threadIdx.x & 63;
    int wave = (blockIdx.x * 256 + threadIdx.x) >> 6;
    int nWaves = gemmBlocks * 4;

    float w[D];
#pragma unroll
    for (int k = 0; k < D; ++k) w[k] = W[k * D + lane];

    for (int r = wave; r < nNodes; r += nWaves) {
        int rr = __builtin_amdgcn_readfirstlane(r);
        const float4* xr = (const float4*)(X + (size_t)rr * D);
        float acc = 0.f;
#pragma unroll
        for (int k4 = 0; k4 < D / 4; ++k4) {
            float4 xv = xr[k4];
            acc = fmaf(xv.x, w[4 * k4 + 0], acc);
            acc = fmaf(xv.y, w[4 * k4 + 1], acc);
            acc = fmaf(xv.z, w[4 * k4 + 2], acc);
            acc = fmaf(xv.w, w[4 * k4 + 3], acc);
        }
        Xp[(size_t)rr * D + lane] = __float2half(acc);
    }
}

// ---------------------------------------------------------------------------
// Kernel 2: fused SDDMM + SpMM.
// One 8-lane group per destination node (8 nodes/wave); lane j holds dims
// 8j..8j+7 (one uint4 of f16).
//
// 3-stage register pipeline per 4-edge batch:
//   iter i issues:  col loads for batch i+2   (no dependencies)
//                   gathers  for batch i+1    (cols arrived 1 iter ago)
//                   compute  of  batch i      (gathers arrived 1 iter ago)
// so no s_waitcnt in the loop waits on a load issued in the same iteration —
// the previous version gathered from cols loaded in the SAME iteration,
// serializing a full cache latency per batch.
// ---------------------------------------------------------------------------
__global__ __launch_bounds__(256) void fused_kernel(const __half* __restrict__ Xp,
                                                    const int* __restrict__ rowptr,
                                                    const int* __restrict__ col,
                                                    const float* __restrict__ attn_w,
                                                    float* __restrict__ out,
                                                    int nNodes) {
    int lane = threadIdx.x & 63;
    int waveId = (blockIdx.x * 256 + threadIdx.x) >> 6;
    int g = lane >> 3;        // node slot within wave
    int j = lane & 7;         // dim chunk: dims 8j..8j+7

    int node = waveId * 8 + g;
    bool active = node < nNodes;
    int nd = active ? node : 0;

    int eStart = rowptr[nd];
    int eEnd   = active ? rowptr[nd + 1] : eStart;

    const uint4* XpV = (const uint4*)Xp;              // row stride = 8 uint4
    uint4 xr = XpV[(size_t)nd * 8 + j];               // dst row chunk (f16)

    float acc[8] = {0.f, 0.f, 0.f, 0.f, 0.f, 0.f, 0.f, 0.f};

    // ---- pipeline prologue ----
    int  cB[4];               // cols for the batch one ahead of compute
    bool vA[4], vB[4];        // validity: compute batch / next batch
    uint4 gA[4];              // gathered src rows for the compute batch
    {
        int cA[4];
#pragma unroll
        for (int u = 0; u < 4; ++u) {                 // cols batch 0
            int ee = eStart + u;
            vA[u] = ee < eEnd;
            cA[u] = col[vA[u] ? ee : 0];
        }
#pragma unroll
        for (int u = 0; u < 4; ++u) {                 // cols batch 1
            int ee = eStart + 4 + u;
            vB[u] = ee < eEnd;
            cB[u] = col[vB[u] ? ee : 0];
        }
#pragma unroll
        for (int u = 0; u < 4; ++u)                   // gathers batch 0
            gA[u] = XpV[(size_t)cA[u] * 8 + j];
    }

    for (int e = eStart; e < eEnd; e += 4) {
        // ---- stage 1: cols for batch i+2 (independent, issue first) ----
        int  cC[4]; bool vC[4];
#pragma unroll
        for (int u = 0; u < 4; ++u) {
            int ee = e + 8 + u;
            vC[u] = ee < eEnd;
            cC[u] = col[vC[u] ? ee : 0];
        }
        // ---- stage 2: gathers for batch i+1 (cols from last iteration) ----
        uint4 gB[4];
#pragma unroll
        for (int u = 0; u < 4; ++u)
            gB[u] = XpV[(size_t)cB[u] * 8 + j];

        // ---- stage 3: compute batch i (gathers from last iteration) ----
        float p[4];
#pragma unroll
        for (int u = 0; u < 4; ++u) p[u] = dot8_f16(xr, gA[u], 0.f);
#pragma unroll
        for (int off = 1; off < 8; off <<= 1)
#pragma unroll
            for (int u = 0; u < 4; ++u) p[u] += __shfl_xor(p[u], off, 64);
#pragma unroll
        for (int u = 0; u < 4; ++u) {
            float s = vA[u] ? p[u] : 0.f;             // attn deferred to epilogue
            fma8_mix(gA[u], s, acc);
        }

        // ---- rotate pipeline registers ----
#pragma unroll
        for (int u = 0; u < 4; ++u) {
            vA[u] = vB[u];
            vB[u] = vC[u];
            cB[u] = cC[u];
            gA[u] = gB[u];
        }
    }

    if (active) {
        float attn = attn_w[0];
        f32x4* o = (f32x4*)(out + (size_t)node * D + 8 * j);
        f32x4 o0 = {attn * acc[0], attn * acc[1], attn * acc[2], attn * acc[3]};
        f32x4 o1 = {attn * acc[4], attn * acc[5], attn * acc[6], attn * acc[7]};
        __builtin_nontemporal_store(o0, o);           // out is never re-read:
        __builtin_nontemporal_store(o1, o + 1);       // keep L2 for Xp gathers
    }
}

extern "C" void kernel_launch(void* const* d_in, const int* in_sizes, int n_in,
                              void* d_out, int out_size, void* d_ws, size_t ws_size,
                              hipStream_t stream) {
    const float* X    = (const float*)d_in[0];
    const float* W    = (const float*)d_in[1];
    const float* attn = (const float*)d_in[2];
    const int*   row  = (const int*)d_in[3];
    const int*   col  = (const int*)d_in[4];
    float* out = (float*)d_out;

    int nNodes = in_sizes[0] / D;
    int nEdges = in_sizes[3];

    // workspace layout: Xp_f16 [nNodes*D] | rowptr [nNodes+1]
    __half* Xp  = (__half*)d_ws;
    int* rowptr = (int*)((char*)d_ws + (size_t)nNodes * D * sizeof(__half));

    int gemmBlocks = 1024;
    int rpBlocks   = (nEdges + 255) / 256;
    prep_kernel<<<gemmBlocks + rpBlocks, 256, 0, stream>>>(X, W, row, Xp, rowptr,
                                                           nNodes, nEdges, gemmBlocks);

    int waves = (nNodes + 7) / 8;                        // 8 nodes per wave
    fused_kernel<<<(waves + 3) / 4, 256, 0, stream>>>(Xp, rowptr, col, attn, out, nNodes);
}

// Round 3
// 103.417 us; speedup vs baseline: 1.0314x; 1.0314x over previous
//
#include <hip/hip_runtime.h>
#include <hip/hip_fp16.h>

#define D 64

typedef _Float16 h16;
typedef h16 h16x2 __attribute__((ext_vector_type(2)));
typedef float f32x4 __attribute__((ext_vector_type(4)));

__device__ __forceinline__ h16x2 u2h(unsigned int u) {
    union { unsigned int i; h16x2 h; } t; t.i = u; return t.h;
}

// dot of 8 f16 pairs (two uint4-packed rows), f32 accumulate
__device__ __forceinline__ float dot8_f16(uint4 a, uint4 b, float c) {
#if __has_builtin(__builtin_amdgcn_fdot2)
    c = __builtin_amdgcn_fdot2(u2h(a.x), u2h(b.x), c, false);
    c = __builtin_amdgcn_fdot2(u2h(a.y), u2h(b.y), c, false);
    c = __builtin_amdgcn_fdot2(u2h(a.z), u2h(b.z), c, false);
    c = __builtin_amdgcn_fdot2(u2h(a.w), u2h(b.w), c, false);
    return c;
#else
    float2 t;
    t = __half22float2(*(const __half2*)&a.x); float2 s = __half22float2(*(const __half2*)&b.x);
    c = fmaf(t.x, s.x, c); c = fmaf(t.y, s.y, c);
    t = __half22float2(*(const __half2*)&a.y); s = __half22float2(*(const __half2*)&b.y);
    c = fmaf(t.x, s.x, c); c = fmaf(t.y, s.y, c);
    t = __half22float2(*(const __half2*)&a.z); s = __half22float2(*(const __half2*)&b.z);
    c = fmaf(t.x, s.x, c); c = fmaf(t.y, s.y, c);
    t = __half22float2(*(const __half2*)&a.w); s = __half22float2(*(const __half2*)&b.w);
    c = fmaf(t.x, s.x, c); c = fmaf(t.y, s.y, c);
    return c;
#endif
}

// acc[q] += (float)x.h[q] * s  — folds to v_fma_mix_f32
__device__ __forceinline__ void fma8_mix(uint4 x, float s, float acc[8]) {
    union { uint4 u; __half h[8]; } t; t.u = x;
#pragma unroll
    for (int q = 0; q < 8; ++q) acc[q] = fmaf(__half2float(t.h[q]), s, acc[q]);
}

// ---------------------------------------------------------------------------
// Kernel 1 (merged): blocks [0, gemmBlocks) compute Xp = f16(X @ W);
// blocks [gemmBlocks, ...) build CSR rowptr from sorted `row`.
// (unchanged — not the bottleneck)
// ---------------------------------------------------------------------------
__global__ __launch_bounds__(256) void prep_kernel(const float* __restrict__ X,
                                                   const float* __restrict__ W,
                                                   const int* __restrict__ row,
                                                   __half* __restrict__ Xp,
                                                   int* __restrict__ rowptr,
                                                   int nNodes, int nEdges,
                                                   int gemmBlocks) {
    if ((int)blockIdx.x >= gemmBlocks) {
        int e = (blockIdx.x - gemmBlocks) * 256 + threadIdx.x;
        if (e >= nEdges) return;
        int r = row[e];
        int rprev = (e == 0) ? -1 : row[e - 1];
        for (int q = rprev + 1; q <= r; ++q) rowptr[q] = e;
        if (e == nEdges - 1) {
            for (int q = r + 1; q <= nNodes; ++q) rowptr[q] = nEdges;
        }
        return;
    }
    int lane = threadIdx.x & 63;
    int wave = (blockIdx.x * 256 + threadIdx.x) >> 6;
    int nWaves = gemmBlocks * 4;

    float w[D];
#pragma unroll
    for (int k = 0; k < D; ++k) w[k] = W[k * D + lane];

    for (int r = wave; r < nNodes; r += nWaves) {
        int rr = __builtin_amdgcn_readfirstlane(r);
        const float4* xr = (const float4*)(X + (size_t)rr * D);
        float acc = 0.f;
#pragma unroll
        for (int k4 = 0; k4 < D / 4; ++k4) {
            float4 xv = xr[k4];
            acc = fmaf(xv.x, w[4 * k4 + 0], acc);
            acc = fmaf(xv.y, w[4 * k4 + 1], acc);
            acc = fmaf(xv.z, w[4 * k4 + 2], acc);
            acc = fmaf(xv.w, w[4 * k4 + 3], acc);
        }
        Xp[(size_t)rr * D + lane] = __float2half(acc);
    }
}

// ---------------------------------------------------------------------------
// Kernel 2: fused SDDMM + SpMM (round-0 proven body + 2-way edge split).
// 4 nodes per wave; each node owned by a PAIR of 8-lane groups (g = 2*slot+half)
// that each process half of the node's edge list. Doubles wave count
// (6250 -> 12500, ~12 waves/SIMD) for gather-latency hiding and halves the
// per-wave divergence quantum. Halves combine with one extra shfl_xor(8)
// stage — no atomics, deterministic.
// Lane j = lane&7 holds dims 8j..8j+7 (one uint4 of f16).
// ---------------------------------------------------------------------------
__global__ __launch_bounds__(256) void fused_kernel(const __half* __restrict__ Xp,
                                                    const int* __restrict__ rowptr,
                                                    const int* __restrict__ col,
                                                    const float* __restrict__ attn_w,
                                                    float* __restrict__ out,
                                                    int nNodes) {
    int lane = threadIdx.x & 63;
    int waveId = (blockIdx.x * 256 + threadIdx.x) >> 6;
    int g = lane >> 3;        // group 0..7
    int j = lane & 7;         // dim chunk: dims 8j..8j+7
    int slot = g >> 1;        // node slot 0..3
    int half = g & 1;         // which half of the edge list

    int node = waveId * 4 + slot;
    bool active = node < nNodes;
    int nd = active ? node : 0;

    int s0 = rowptr[nd];
    int e0 = active ? rowptr[nd + 1] : s0;
    int mid = s0 + ((e0 - s0 + 1) >> 1);
    int eStart = half ? mid : s0;
    int eEnd   = half ? e0  : mid;

    const uint4* XpV = (const uint4*)Xp;              // row stride = 8 uint4
    uint4 xr = XpV[(size_t)nd * 8 + j];               // dst row chunk (f16)

    float acc[8] = {0.f, 0.f, 0.f, 0.f, 0.f, 0.f, 0.f, 0.f};

    // prologue: load batch 0 (safe index 0 for out-of-range slots)
    bool v[4]; uint4 raw[4];
#pragma unroll
    for (int u = 0; u < 4; ++u) {
        int ee = eStart + u;
        v[u] = ee < eEnd;
        int cc = col[v[u] ? ee : 0];
        raw[u] = XpV[(size_t)cc * 8 + j];
    }

    for (int e = eStart; e < eEnd; e += 4) {
        // ---- issue batch i+1 loads first (overlap with batch i compute) ----
        bool v2[4]; uint4 raw2[4];
#pragma unroll
        for (int u = 0; u < 4; ++u) {
            int ee = e + 4 + u;
            v2[u] = ee < eEnd;
            int cc = col[v2[u] ? ee : 0];
            raw2[u] = XpV[(size_t)cc * 8 + j];
        }
        // ---- consume batch i ----
        float p[4];
#pragma unroll
        for (int u = 0; u < 4; ++u) p[u] = dot8_f16(xr, raw[u], 0.f);
#pragma unroll
        for (int off = 1; off < 8; off <<= 1)
#pragma unroll
            for (int u = 0; u < 4; ++u) p[u] += __shfl_xor(p[u], off, 64);
#pragma unroll
        for (int u = 0; u < 4; ++u) {
            float s = v[u] ? p[u] : 0.f;              // attn deferred to epilogue
            fma8_mix(raw[u], s, acc);
        }
        // ---- rotate ----
#pragma unroll
        for (int u = 0; u < 4; ++u) { v[u] = v2[u]; raw[u] = raw2[u]; }
    }

    // ---- combine the two halves of each node (lanes l <-> l^8) ----
#pragma unroll
    for (int q = 0; q < 8; ++q) acc[q] += __shfl_xor(acc[q], 8, 64);

    if (active && half == 0) {
        float attn = attn_w[0];
        f32x4* o = (f32x4*)(out + (size_t)node * D + 8 * j);
        f32x4 o0 = {attn * acc[0], attn * acc[1], attn * acc[2], attn * acc[3]};
        f32x4 o1 = {attn * acc[4], attn * acc[5], attn * acc[6], attn * acc[7]};
        __builtin_nontemporal_store(o0, o);           // out is never re-read:
        __builtin_nontemporal_store(o1, o + 1);       // keep L2 for Xp gathers
    }
}

extern "C" void kernel_launch(void* const* d_in, const int* in_sizes, int n_in,
                              void* d_out, int out_size, void* d_ws, size_t ws_size,
                              hipStream_t stream) {
    const float* X    = (const float*)d_in[0];
    const float* W    = (const float*)d_in[1];
    const float* attn = (const float*)d_in[2];
    const int*   row  = (const int*)d_in[3];
    const int*   col  = (const int*)d_in[4];
    float* out = (float*)d_out;

    int nNodes = in_sizes[0] / D;
    int nEdges = in_sizes[3];

    // workspace layout: Xp_f16 [nNodes*D] | rowptr [nNodes+1]
    __half* Xp  = (__half*)d_ws;
    int* rowptr = (int*)((char*)d_ws + (size_t)nNodes * D * sizeof(__half));

    int gemmBlocks = 1024;
    int rpBlocks   = (nEdges + 255) / 256;
    prep_kernel<<<gemmBlocks + rpBlocks, 256, 0, stream>>>(X, W, row, Xp, rowptr,
                                                           nNodes, nEdges, gemmBlocks);

    int waves = (nNodes + 3) / 4;                        // 4 nodes per wave
    fused_kernel<<<(waves + 3) / 4, 256, 0, stream>>>(Xp, rowptr, col, attn, out, nNodes);
}